// Round 1
// baseline (758.484 us; speedup 1.0000x reference)
//
#include <hip/hip_runtime.h>
#include <cstdint>
#include <cfloat>

#define BATCH 16
#define NBOX 25200
#define CH 85
#define NCLS 80
#define CAP 512
#define ACC 48
#define MAXDET 300

typedef unsigned long long u64;

// ---------------- kernel 0: zero the per-(image,class) counters ----------------
__global__ void zero_cnt_kernel(int* __restrict__ cnt) {
    int t = blockIdx.x * blockDim.x + threadIdx.x;
    if (t < BATCH * NCLS) cnt[t] = 0;
}

// ---------------- kernel A: per-row conf/argmax + bucket by (image,class) ------
// one wave (64 lanes) per row of 85 floats
__global__ __launch_bounds__(256) void pre_kernel(const float* __restrict__ p,
                                                  int* __restrict__ cnt,
                                                  u64* __restrict__ bucketKey) {
#pragma clang fp contract(off)
    int lane = threadIdx.x & 63;
    int wid = (blockIdx.x << 2) | (threadIdx.x >> 6);   // row index in [0, BATCH*NBOX)
    long base = (long)wid * CH;
    float e1 = p[base + lane];
    float e2 = (lane < CH - 64) ? p[base + 64 + lane] : -FLT_MAX;
    float obj = __shfl(e1, 4);

    // local class candidates: e1 covers classes (lane-5) for lane>=5,
    // e2 covers classes (lane+59) for lane<21
    float v = -FLT_MAX; int c = 1000;
    if (lane >= 5) { v = e1 * obj; c = lane - 5; }
    if (lane < 21) {
        float v2 = e2 * obj; int c2 = lane + 59;
        if (v2 > v || (v2 == v && c2 < c)) { v = v2; c = c2; }
    }
    // wave max with (value desc, class asc) tie-break == np.argmax first-max
    for (int off = 32; off; off >>= 1) {
        float v2 = __shfl_xor(v, off);
        int   c2 = __shfl_xor(c, off);
        if (v2 > v || (v2 == v && c2 < c)) { v = v2; c = c2; }
    }

    if (lane == 0 && obj > 0.25f && v > 0.25f) {
        int b   = wid / NBOX;
        int idx = wid - b * NBOX;               // < 25200 < 2^15
        // key: (conf bits)<<22 | (32767-idx)<<7 | class  -> desc sort = (conf desc, idx asc)
        u64 key = ((u64)__float_as_uint(v) << 22) | ((u64)(32767 - idx) << 7) | (u64)c;
        int pos = atomicAdd(&cnt[b * NCLS + c], 1);
        if (pos < CAP) bucketKey[(long)(b * NCLS + c) * CAP + pos] = key;
    }
}

// ---------------- kernel B: per-(image,class) sort + greedy NMS ----------------
__global__ __launch_bounds__(256) void nms_kernel(const float* __restrict__ p,
                                                  const int* __restrict__ cnt,
                                                  const u64* __restrict__ bucketKey,
                                                  u64* __restrict__ accKey) {
#pragma clang fp contract(off)
    __shared__ u64   keys[CAP];
    __shared__ float bx1[CAP], by1[CAP], bx2[CAP], by2[CAP], ar[CAP];
    __shared__ int   keepf[CAP];
    __shared__ u64   accLoc[ACC];

    int tid = threadIdx.x;
    int c = blockIdx.x, b = blockIdx.y;
    int n = cnt[b * NCLS + c]; if (n > CAP) n = CAP;

    for (int t = tid; t < CAP; t += 256)
        keys[t] = (t < n) ? bucketKey[(long)(b * NCLS + c) * CAP + t] : 0ULL;
    __syncthreads();

    // bitonic sort, descending, CAP=512 elements, exactly 256 pairs per step
    for (int k = 2; k <= CAP; k <<= 1)
        for (int j = k >> 1; j > 0; j >>= 1) {
            int t = tid;
            int i  = ((t & ~(j - 1)) << 1) | (t & (j - 1));
            int pj = i | j;
            u64 a = keys[i], d = keys[pj];
            if (((i & k) == 0) ? (a < d) : (a > d)) { keys[i] = d; keys[pj] = a; }
            __syncthreads();
        }

    // gather offset boxes (bit-exact reference op order: xyxy first, then +j*4096)
    float off = (float)c * 4096.0f;
    for (int t = tid; t < CAP; t += 256) {
        keepf[t] = (t < n) ? 1 : 0;
        if (t < n) {
            int idx = 32767 - (int)((keys[t] >> 7) & 32767);
            long pb = ((long)b * NBOX + idx) * CH;
            float x = p[pb], y = p[pb + 1], w = p[pb + 2], h = p[pb + 3];
            float hw = w * 0.5f, hh = h * 0.5f;
            float X1 = (x - hw) + off, Y1 = (y - hh) + off;
            float X2 = (x + hw) + off, Y2 = (y + hh) + off;
            bx1[t] = X1; by1[t] = Y1; bx2[t] = X2; by2[t] = Y2;
            ar[t] = (X2 - X1) * (Y2 - Y1);
        }
    }
    __syncthreads();

    // greedy NMS on sorted order
    for (int i = 0; i < n; i++) {
        if (keepf[i]) {
            for (int jj = i + 1 + tid; jj < n; jj += 256) {
                float xx1 = fmaxf(bx1[i], bx1[jj]);
                float yy1 = fmaxf(by1[i], by1[jj]);
                float xx2 = fminf(bx2[i], bx2[jj]);
                float yy2 = fminf(by2[i], by2[jj]);
                float inter = fmaxf(xx2 - xx1, 0.0f) * fmaxf(yy2 - yy1, 0.0f);
                float uni = (ar[i] + ar[jj]) - inter;
                if (inter / uni > 0.45f) keepf[jj] = 0;
            }
        }
        __syncthreads();
    }

    // compact first ACC accepted keys (sorted order preserved)
    for (int t = tid; t < ACC; t += 256) accLoc[t] = 0ULL;
    __syncthreads();
    if (tid < 64) {
        int baseCnt = 0;
        for (int chunk = 0; chunk < CAP / 64; chunk++) {
            int e = chunk * 64 + tid;
            int kp = (e < n) ? keepf[e] : 0;
            u64 m = __ballot(kp);
            if (kp) {
                int pos = baseCnt + __popcll(m & ((1ULL << tid) - 1ULL));
                if (pos < ACC) accLoc[pos] = keys[e];
            }
            baseCnt += __popcll(m);
        }
    }
    __syncthreads();
    for (int t = tid; t < ACC; t += 256)
        accKey[(long)(b * NCLS + c) * ACC + t] = accLoc[t];
}

// ---------------- kernel C: per-image merge of 80 sorted lists -> top 300 ------
__global__ __launch_bounds__(256) void merge_kernel(const float* __restrict__ p,
                                                    const u64* __restrict__ accKey,
                                                    float* __restrict__ outRows,
                                                    float* __restrict__ outKeep) {
#pragma clang fp contract(off)
    __shared__ u64 keys[4096];
    int tid = threadIdx.x, b = blockIdx.x;
    for (int t = tid; t < 4096; t += 256)
        keys[t] = (t < NCLS * ACC) ? accKey[(long)b * NCLS * ACC + t] : 0ULL;
    __syncthreads();

    for (int k = 2; k <= 4096; k <<= 1)
        for (int j = k >> 1; j > 0; j >>= 1) {
            for (int t = tid; t < 2048; t += 256) {
                int i  = ((t & ~(j - 1)) << 1) | (t & (j - 1));
                int pj = i | j;
                u64 a = keys[i], d = keys[pj];
                if (((i & k) == 0) ? (a < d) : (a > d)) { keys[i] = d; keys[pj] = a; }
            }
            __syncthreads();
        }

    for (int t = tid; t < MAXDET; t += 256) {
        u64 key = keys[t];
        float r0 = 0, r1 = 0, r2 = 0, r3 = 0, r4 = 0, r5 = 0, kp = 0;
        if (key) {
            int c   = (int)(key & 127);
            int idx = 32767 - (int)((key >> 7) & 32767);
            float conf = __uint_as_float((unsigned)(key >> 22));
            long pb = ((long)b * NBOX + idx) * CH;
            float x = p[pb], y = p[pb + 1], w = p[pb + 2], h = p[pb + 3];
            float hw = w * 0.5f, hh = h * 0.5f;
            r0 = x - hw; r1 = y - hh; r2 = x + hw; r3 = y + hh;
            r4 = conf; r5 = (float)c; kp = 1.0f;
        }
        float* row = outRows + ((long)b * MAXDET + t) * 6;
        row[0] = r0; row[1] = r1; row[2] = r2;
        row[3] = r3; row[4] = r4; row[5] = r5;
        outKeep[b * MAXDET + t] = kp;
    }
}

extern "C" void kernel_launch(void* const* d_in, const int* in_sizes, int n_in,
                              void* d_out, int out_size, void* d_ws, size_t ws_size,
                              hipStream_t stream) {
    const float* p = (const float*)d_in[0];
    float* out = (float*)d_out;

    char* ws = (char*)d_ws;
    int* cnt = (int*)ws;                                              // 1280 ints
    u64* bucketKey = (u64*)(ws + 8192);                               // 1280*512*8 = 5.24 MB
    u64* accKey    = (u64*)(ws + 8192 + (size_t)BATCH * NCLS * CAP * 8); // 1280*48*8

    zero_cnt_kernel<<<(BATCH * NCLS + 255) / 256, 256, 0, stream>>>(cnt);
    pre_kernel<<<(BATCH * NBOX) / 4, 256, 0, stream>>>(p, cnt, bucketKey);
    dim3 gB(NCLS, BATCH);
    nms_kernel<<<gB, 256, 0, stream>>>(p, cnt, bucketKey, accKey);
    merge_kernel<<<BATCH, 256, 0, stream>>>(p, accKey, out, out + (size_t)BATCH * MAXDET * 6);
}

// Round 2
// 542.876 us; speedup vs baseline: 1.3972x; 1.3972x over previous
//
#include <hip/hip_runtime.h>
#include <cstdint>
#include <cfloat>

#define BATCH 16
#define NBOX 25200
#define CH 85
#define NCLS 80
#define CAP 512
#define ACC 48
#define MAXDET 300
#define RPB 128      // rows per block in pre_kernel

typedef unsigned long long u64;

// ---------------- kernel A: staged per-row conf/argmax + bucket by (image,class)
// 256 threads stage 128 rows into LDS coalesced, then 2 threads per row scan classes.
__global__ __launch_bounds__(256) void pre_kernel(const float* __restrict__ p,
                                                  int* __restrict__ cnt,
                                                  u64* __restrict__ bucketKey) {
#pragma clang fp contract(off)
    __shared__ float s[RPB * CH];          // 43,520 B
    int tid = threadIdx.x;
    long blockRow = (long)blockIdx.x * RPB;

    // coalesced float4 staging: 2720 float4 per block, start 16B-aligned
    const float4* p4 = (const float4*)(p + blockRow * CH);
    float4* s4 = (float4*)s;
    for (int t = tid; t < RPB * CH / 4; t += 256) s4[t] = p4[t];
    __syncthreads();

    int r = tid >> 1;                      // row 0..127
    int half = tid & 1;                    // classes [0,40) vs [40,80)
    const float* row = s + r * CH;
    float obj = row[4];

    float v = -FLT_MAX; int c = 1000;
    int c0 = half * 40;
    for (int k = 0; k < 40; k++) {
        float sc = row[5 + c0 + k] * obj;  // multiply-first, matches reference
        int cc = c0 + k;
        if (sc > v) { v = sc; c = cc; }    // strict > keeps first max
    }
    // combine halves: prefer strictly greater, tie -> lower class (first max)
    float v2 = __shfl_xor(v, 1);
    int   cz = __shfl_xor(c, 1);
    if (v2 > v || (v2 == v && cz < c)) { v = v2; c = cz; }

    if (half == 0 && obj > 0.25f && v > 0.25f) {
        int wid = (int)blockRow + r;
        int b   = wid / NBOX;
        int idx = wid - b * NBOX;          // < 25200 < 2^15
        // key: (conf bits)<<22 | (32767-idx)<<7 | class -> desc = (conf desc, idx asc)
        u64 key = ((u64)__float_as_uint(v) << 22) | ((u64)(32767 - idx) << 7) | (u64)c;
        int pos = atomicAdd(&cnt[b * NCLS + c], 1);
        if (pos < CAP) bucketKey[(long)(b * NCLS + c) * CAP + pos] = key;
    }
}

// ---------------- kernel B: per-(image,class) sort + bitmask greedy NMS --------
__global__ __launch_bounds__(256) void nms_kernel(const float* __restrict__ p,
                                                  const int* __restrict__ cnt,
                                                  const u64* __restrict__ bucketKey,
                                                  u64* __restrict__ accKey) {
#pragma clang fp contract(off)
    __shared__ u64   keys[CAP];
    __shared__ float bx1[CAP], by1[CAP], bx2[CAP], by2[CAP], ar[CAP];
    __shared__ u64   M[CAP * 8];           // suppression bit-matrix, 32 KB
    __shared__ u64   accLoc[ACC];

    int tid = threadIdx.x;
    int c = blockIdx.x, b = blockIdx.y;
    int n = cnt[b * NCLS + c]; if (n > CAP) n = CAP;

    for (int t = tid; t < CAP; t += 256)
        keys[t] = (t < n) ? bucketKey[(long)(b * NCLS + c) * CAP + t] : 0ULL;
    for (int t = tid; t < ACC; t += 256) accLoc[t] = 0ULL;
    __syncthreads();

    // bitonic sort descending over the smallest pow2 >= n (zeros sink to tail)
    int m = 64; while (m < n) m <<= 1;
    for (int k = 2; k <= m; k <<= 1)
        for (int j = k >> 1; j > 0; j >>= 1) {
            if (tid < (m >> 1)) {
                int i  = ((tid & ~(j - 1)) << 1) | (tid & (j - 1));
                int pj = i | j;
                u64 a = keys[i], d = keys[pj];
                if (((i & k) == 0) ? (a < d) : (a > d)) { keys[i] = d; keys[pj] = a; }
            }
            __syncthreads();
        }

    // gather offset boxes (bit-exact reference op order: xyxy first, then +c*4096)
    float off = (float)c * 4096.0f;
    for (int t = tid; t < n; t += 256) {
        int idx = 32767 - (int)((keys[t] >> 7) & 32767);
        long pb = ((long)b * NBOX + idx) * CH;
        float x = p[pb], y = p[pb + 1], w = p[pb + 2], h = p[pb + 3];
        float hw = w * 0.5f, hh = h * 0.5f;
        float X1 = (x - hw) + off, Y1 = (y - hh) + off;
        float X2 = (x + hw) + off, Y2 = (y + hh) + off;
        bx1[t] = X1; by1[t] = Y1; bx2[t] = X2; by2[t] = Y2;
        ar[t] = (X2 - X1) * (Y2 - Y1);
    }
    __syncthreads();

    // build upper-triangular suppression matrix: M[i][w] bit j-w*64 = iou(i,j)>thres, j>i
    int W = (n + 63) >> 6;
    int total = n * W;
    for (int t = tid; t < total; t += 256) {
        int i = t / W, w = t - i * W;
        u64 bits = 0;
        int jlo = w << 6;
        int jhi = jlo + 64; if (jhi > n) jhi = n;
        int j0 = i + 1; if (j0 < jlo) j0 = jlo;
        if (j0 < jhi) {
            float X1 = bx1[i], Y1 = by1[i], X2 = bx2[i], Y2 = by2[i], A = ar[i];
            for (int j = j0; j < jhi; j++) {
                float xx1 = fmaxf(X1, bx1[j]);
                float yy1 = fmaxf(Y1, by1[j]);
                float xx2 = fminf(X2, bx2[j]);
                float yy2 = fminf(Y2, by2[j]);
                float inter = fmaxf(xx2 - xx1, 0.0f) * fmaxf(yy2 - yy1, 0.0f);
                float uni = (A + ar[j]) - inter;
                if (inter / uni > 0.45f) bits |= 1ULL << (j - jlo);
            }
        }
        M[i * 8 + w] = bits;
    }
    __syncthreads();

    // greedy scan by one wave: lane w holds live-word w, barrier-free
    if (tid < 64) {
        int lane = tid;
        u64 live = 0;
        if (lane < W) {
            int lo = lane << 6;
            int nb = n - lo; if (nb > 64) nb = 64;
            live = (nb >= 64) ? ~0ULL : ((1ULL << nb) - 1ULL);
        }
        int nacc = 0;
        for (int i = 0; i < n; i++) {
            u64 lw = __shfl(live, i >> 6);
            if ((lw >> (i & 63)) & 1ULL) {       // wave-uniform branch
                if (lane == 0 && nacc < ACC) accLoc[nacc] = keys[i];
                nacc++;
                u64 mm = (lane < W) ? M[i * 8 + lane] : 0ULL;
                live &= ~mm;
            }
        }
    }
    __syncthreads();
    for (int t = tid; t < ACC; t += 256)
        accKey[(long)(b * NCLS + c) * ACC + t] = accLoc[t];
}

// ---------------- kernel C: per-image merge of 80 sorted lists -> top 300 ------
__global__ __launch_bounds__(256) void merge_kernel(const float* __restrict__ p,
                                                    const u64* __restrict__ accKey,
                                                    float* __restrict__ outRows,
                                                    float* __restrict__ outKeep) {
#pragma clang fp contract(off)
    __shared__ u64 keys[4096];
    int tid = threadIdx.x, b = blockIdx.x;
    for (int t = tid; t < 4096; t += 256)
        keys[t] = (t < NCLS * ACC) ? accKey[(long)b * NCLS * ACC + t] : 0ULL;
    __syncthreads();

    for (int k = 2; k <= 4096; k <<= 1)
        for (int j = k >> 1; j > 0; j >>= 1) {
            for (int t = tid; t < 2048; t += 256) {
                int i  = ((t & ~(j - 1)) << 1) | (t & (j - 1));
                int pj = i | j;
                u64 a = keys[i], d = keys[pj];
                if (((i & k) == 0) ? (a < d) : (a > d)) { keys[i] = d; keys[pj] = a; }
            }
            __syncthreads();
        }

    for (int t = tid; t < MAXDET; t += 256) {
        u64 key = keys[t];
        float r0 = 0, r1 = 0, r2 = 0, r3 = 0, r4 = 0, r5 = 0, kp = 0;
        if (key) {
            int cc  = (int)(key & 127);
            int idx = 32767 - (int)((key >> 7) & 32767);
            float conf = __uint_as_float((unsigned)(key >> 22));
            long pb = ((long)b * NBOX + idx) * CH;
            float x = p[pb], y = p[pb + 1], w = p[pb + 2], h = p[pb + 3];
            float hw = w * 0.5f, hh = h * 0.5f;
            r0 = x - hw; r1 = y - hh; r2 = x + hw; r3 = y + hh;
            r4 = conf; r5 = (float)cc; kp = 1.0f;
        }
        float* row = outRows + ((long)b * MAXDET + t) * 6;
        row[0] = r0; row[1] = r1; row[2] = r2;
        row[3] = r3; row[4] = r4; row[5] = r5;
        outKeep[b * MAXDET + t] = kp;
    }
}

extern "C" void kernel_launch(void* const* d_in, const int* in_sizes, int n_in,
                              void* d_out, int out_size, void* d_ws, size_t ws_size,
                              hipStream_t stream) {
    const float* p = (const float*)d_in[0];
    float* out = (float*)d_out;

    char* ws = (char*)d_ws;
    int* cnt = (int*)ws;                                                  // 1280 ints
    u64* bucketKey = (u64*)(ws + 8192);                                   // 5.24 MB
    u64* accKey    = (u64*)(ws + 8192 + (size_t)BATCH * NCLS * CAP * 8);  // 491 KB

    hipMemsetAsync(cnt, 0, BATCH * NCLS * sizeof(int), stream);
    pre_kernel<<<(BATCH * NBOX) / RPB, 256, 0, stream>>>(p, cnt, bucketKey);
    dim3 gB(NCLS, BATCH);
    nms_kernel<<<gB, 256, 0, stream>>>(p, cnt, bucketKey, accKey);
    merge_kernel<<<BATCH, 256, 0, stream>>>(p, accKey, out, out + (size_t)BATCH * MAXDET * 6);
}

// Round 3
// 536.272 us; speedup vs baseline: 1.4144x; 1.0123x over previous
//
#include <hip/hip_runtime.h>
#include <cstdint>
#include <cfloat>

#define BATCH 16
#define NBOX 25200
#define CH 85
#define NCLS 80
#define CAP 512
#define ACC 48
#define MAXDET 300
#define RPB 128      // rows per block in pre_kernel

typedef unsigned long long u64;

// ---------------- kernel A: staged per-row conf/argmax + bucket by (image,class)
__global__ __launch_bounds__(256) void pre_kernel(const float* __restrict__ p,
                                                  int* __restrict__ cnt,
                                                  u64* __restrict__ bucketKey) {
#pragma clang fp contract(off)
    __shared__ float s[RPB * CH];          // 43,520 B
    int tid = threadIdx.x;
    long blockRow = (long)blockIdx.x * RPB;

    const float4* p4 = (const float4*)(p + blockRow * CH);
    float4* s4 = (float4*)s;
    for (int t = tid; t < RPB * CH / 4; t += 256) s4[t] = p4[t];
    __syncthreads();

    int r = tid >> 1;                      // row 0..127
    int half = tid & 1;                    // classes [0,40) vs [40,80)
    const float* row = s + r * CH;
    float obj = row[4];

    float v = -FLT_MAX; int c = 1000;
    int c0 = half * 40;
    for (int k = 0; k < 40; k++) {
        float sc = row[5 + c0 + k] * obj;  // multiply-first, matches reference
        int cc = c0 + k;
        if (sc > v) { v = sc; c = cc; }    // strict > keeps first max
    }
    float v2 = __shfl_xor(v, 1);
    int   cz = __shfl_xor(c, 1);
    if (v2 > v || (v2 == v && cz < c)) { v = v2; c = cz; }

    if (half == 0 && obj > 0.25f && v > 0.25f) {
        int wid = (int)blockRow + r;
        int b   = wid / NBOX;
        int idx = wid - b * NBOX;          // < 25200 < 2^15
        u64 key = ((u64)__float_as_uint(v) << 22) | ((u64)(32767 - idx) << 7) | (u64)c;
        int pos = atomicAdd(&cnt[b * NCLS + c], 1);
        if (pos < CAP) bucketKey[(long)(b * NCLS + c) * CAP + pos] = key;
    }
}

// ---------------- kernel B: per-(image,class) sort + bitmask greedy NMS --------
__global__ __launch_bounds__(256) void nms_kernel(const float* __restrict__ p,
                                                  const int* __restrict__ cnt,
                                                  const u64* __restrict__ bucketKey,
                                                  u64* __restrict__ accKey) {
#pragma clang fp contract(off)
    __shared__ u64   keys[CAP];
    __shared__ float bx1[CAP], by1[CAP], bx2[CAP], by2[CAP], ar[CAP];
    __shared__ u64   M[CAP * 8];           // suppression bit-matrix, 32 KB
    __shared__ u64   accLoc[ACC];

    int tid = threadIdx.x;
    int c = blockIdx.x, b = blockIdx.y;
    int n = cnt[b * NCLS + c]; if (n > CAP) n = CAP;

    for (int t = tid; t < CAP; t += 256)
        keys[t] = (t < n) ? bucketKey[(long)(b * NCLS + c) * CAP + t] : 0ULL;
    for (int t = tid; t < ACC; t += 256) accLoc[t] = 0ULL;
    __syncthreads();

    // bitonic sort descending over the smallest pow2 >= n (zeros sink to tail)
    int m = 64; while (m < n) m <<= 1;
    for (int k = 2; k <= m; k <<= 1)
        for (int j = k >> 1; j > 0; j >>= 1) {
            if (tid < (m >> 1)) {
                int i  = ((tid & ~(j - 1)) << 1) | (tid & (j - 1));
                int pj = i | j;
                u64 a = keys[i], d = keys[pj];
                if (((i & k) == 0) ? (a < d) : (a > d)) { keys[i] = d; keys[pj] = a; }
            }
            __syncthreads();
        }

    // gather offset boxes (bit-exact reference op order: xyxy first, then +c*4096)
    float off = (float)c * 4096.0f;
    for (int t = tid; t < n; t += 256) {
        int idx = 32767 - (int)((keys[t] >> 7) & 32767);
        long pb = ((long)b * NBOX + idx) * CH;
        float x = p[pb], y = p[pb + 1], w = p[pb + 2], h = p[pb + 3];
        float hw = w * 0.5f, hh = h * 0.5f;
        float X1 = (x - hw) + off, Y1 = (y - hh) + off;
        float X2 = (x + hw) + off, Y2 = (y + hh) + off;
        bx1[t] = X1; by1[t] = Y1; bx2[t] = X2; by2[t] = Y2;
        ar[t] = (X2 - X1) * (Y2 - Y1);
    }
    __syncthreads();

    // build upper-triangular suppression matrix.
    // mapping: consecutive threads -> consecutive i, SAME word w, so the inner
    // j-loop reads bx1[j]... at a wave-uniform address (LDS broadcast, no
    // conflicts) and per-lane bx1[i] reads are stride-1 (2-way, free).
    int W = (n + 63) >> 6;
    int total = W * n;
    for (int t = tid; t < total; t += 256) {
        int w = t / n, i = t - w * n;
        u64 bits = 0;
        int jlo = w << 6;
        int jhi = jlo + 64; if (jhi > n) jhi = n;
        int j0 = i + 1; if (j0 < jlo) j0 = jlo;
        if (j0 < jhi) {
            float X1 = bx1[i], Y1 = by1[i], X2 = bx2[i], Y2 = by2[i], A = ar[i];
            for (int j = j0; j < jhi; j++) {
                float xx1 = fmaxf(X1, bx1[j]);
                float yy1 = fmaxf(Y1, by1[j]);
                float xx2 = fminf(X2, bx2[j]);
                float yy2 = fminf(Y2, by2[j]);
                float inter = fmaxf(xx2 - xx1, 0.0f) * fmaxf(yy2 - yy1, 0.0f);
                float uni = (A + ar[j]) - inter;
                if (inter / uni > 0.45f) bits |= 1ULL << (j - jlo);
            }
        }
        M[i * 8 + w] = bits;
    }
    __syncthreads();

    // greedy: find-next-live-bit loop, iterations == number of accepted boxes.
    // lane w holds live-word w; ballot -> first nonzero word -> ffs -> accept.
    if (tid < 64) {
        int lane = tid;
        u64 live = 0;
        if (lane < W) {
            int lo = lane << 6;
            int nb = n - lo; if (nb > 64) nb = 64;
            live = (nb >= 64) ? ~0ULL : ((1ULL << nb) - 1ULL);
        }
        int nacc = 0;
        for (;;) {
            u64 ball = __ballot(live != 0ULL);
            if (!ball) break;
            int wl  = __ffsll(ball) - 1;
            u64 w0  = __shfl(live, wl);
            int bit = __ffsll(w0) - 1;
            int i   = (wl << 6) + bit;
            if (lane == 0 && nacc < ACC) accLoc[nacc] = keys[i];
            nacc++;
            u64 mm = (lane < W) ? M[i * 8 + lane] : 0ULL;  // 8 consecutive u64: conflict-free
            if (lane == wl) mm |= 1ULL << bit;             // clear the accepted bit too
            live &= ~mm;
        }
    }
    __syncthreads();
    for (int t = tid; t < ACC; t += 256)
        accKey[(long)(b * NCLS + c) * ACC + t] = accLoc[t];
}

// ---------------- kernel C: per-image merge of 80 sorted lists -> top 300 ------
__global__ __launch_bounds__(256) void merge_kernel(const float* __restrict__ p,
                                                    const u64* __restrict__ accKey,
                                                    float* __restrict__ outRows,
                                                    float* __restrict__ outKeep) {
#pragma clang fp contract(off)
    __shared__ u64 keys[4096];
    int tid = threadIdx.x, b = blockIdx.x;
    for (int t = tid; t < 4096; t += 256)
        keys[t] = (t < NCLS * ACC) ? accKey[(long)b * NCLS * ACC + t] : 0ULL;
    __syncthreads();

    for (int k = 2; k <= 4096; k <<= 1)
        for (int j = k >> 1; j > 0; j >>= 1) {
            for (int t = tid; t < 2048; t += 256) {
                int i  = ((t & ~(j - 1)) << 1) | (t & (j - 1));
                int pj = i | j;
                u64 a = keys[i], d = keys[pj];
                if (((i & k) == 0) ? (a < d) : (a > d)) { keys[i] = d; keys[pj] = a; }
            }
            __syncthreads();
        }

    for (int t = tid; t < MAXDET; t += 256) {
        u64 key = keys[t];
        float r0 = 0, r1 = 0, r2 = 0, r3 = 0, r4 = 0, r5 = 0, kp = 0;
        if (key) {
            int cc  = (int)(key & 127);
            int idx = 32767 - (int)((key >> 7) & 32767);
            float conf = __uint_as_float((unsigned)(key >> 22));
            long pb = ((long)b * NBOX + idx) * CH;
            float x = p[pb], y = p[pb + 1], w = p[pb + 2], h = p[pb + 3];
            float hw = w * 0.5f, hh = h * 0.5f;
            r0 = x - hw; r1 = y - hh; r2 = x + hw; r3 = y + hh;
            r4 = conf; r5 = (float)cc; kp = 1.0f;
        }
        float* row = outRows + ((long)b * MAXDET + t) * 6;
        row[0] = r0; row[1] = r1; row[2] = r2;
        row[3] = r3; row[4] = r4; row[5] = r5;
        outKeep[b * MAXDET + t] = kp;
    }
}

extern "C" void kernel_launch(void* const* d_in, const int* in_sizes, int n_in,
                              void* d_out, int out_size, void* d_ws, size_t ws_size,
                              hipStream_t stream) {
    const float* p = (const float*)d_in[0];
    float* out = (float*)d_out;

    char* ws = (char*)d_ws;
    int* cnt = (int*)ws;                                                  // 1280 ints
    u64* bucketKey = (u64*)(ws + 8192);                                   // 5.24 MB
    u64* accKey    = (u64*)(ws + 8192 + (size_t)BATCH * NCLS * CAP * 8);  // 491 KB

    hipMemsetAsync(cnt, 0, BATCH * NCLS * sizeof(int), stream);
    pre_kernel<<<(BATCH * NBOX) / RPB, 256, 0, stream>>>(p, cnt, bucketKey);
    dim3 gB(NCLS, BATCH);
    nms_kernel<<<gB, 256, 0, stream>>>(p, cnt, bucketKey, accKey);
    merge_kernel<<<BATCH, 256, 0, stream>>>(p, accKey, out, out + (size_t)BATCH * MAXDET * 6);
}

// Round 4
// 381.367 us; speedup vs baseline: 1.9889x; 1.4062x over previous
//
#include <hip/hip_runtime.h>
#include <cstdint>
#include <cfloat>

#define BATCH 16
#define NBOX 25200
#define CH 85
#define NCLS 80
#define CAP 512
#define ACC 48
#define MAXDET 300
#define RPB 128      // rows per block in pre_kernel
#define CNTPAD 16    // ints per counter slot (64B line) to kill atomic line contention

typedef unsigned long long u64;

__device__ __forceinline__ u64 shflx64(u64 v, int m) {
    int lo = __shfl_xor((int)(unsigned)(v & 0xffffffffu), m);
    int hi = __shfl_xor((int)(unsigned)(v >> 32), m);
    return ((u64)(unsigned)hi << 32) | (u64)(unsigned)lo;
}

// ---------------- kernel A: staged per-row conf/argmax + bucket by (image,class)
__global__ __launch_bounds__(256) void pre_kernel(const float* __restrict__ p,
                                                  int* __restrict__ cnt,
                                                  u64* __restrict__ bucketKey) {
#pragma clang fp contract(off)
    __shared__ float s[RPB * CH];          // 43,520 B
    int tid = threadIdx.x;
    long blockRow = (long)blockIdx.x * RPB;

    const float4* p4 = (const float4*)(p + blockRow * CH);
    float4* s4 = (float4*)s;
    for (int t = tid; t < RPB * CH / 4; t += 256) s4[t] = p4[t];
    __syncthreads();

    int r = tid >> 1;                      // row 0..127
    int half = tid & 1;                    // classes [0,40) vs [40,80)
    const float* row = s + r * CH;
    float obj = row[4];

    float v = -FLT_MAX; int c = 1000;
    int c0 = half * 40;
    for (int k = 0; k < 40; k++) {
        float sc = row[5 + c0 + k] * obj;  // multiply-first, matches reference
        int cc = c0 + k;
        if (sc > v) { v = sc; c = cc; }    // strict > keeps first max
    }
    float v2 = __shfl_xor(v, 1);
    int   cz = __shfl_xor(c, 1);
    if (v2 > v || (v2 == v && cz < c)) { v = v2; c = cz; }

    if (half == 0 && obj > 0.25f && v > 0.25f) {
        int wid = (int)blockRow + r;
        int b   = wid / NBOX;
        int idx = wid - b * NBOX;          // < 25200 < 2^15
        u64 key = ((u64)__float_as_uint(v) << 22) | ((u64)(32767 - idx) << 7) | (u64)c;
        int bkt = b * NCLS + c;
        int pos = atomicAdd(&cnt[bkt * CNTPAD], 1);
        if (pos < CAP) bucketKey[(long)bkt * CAP + pos] = key;
    }
}

// ---------------- kernel B: wave-per-bucket register-resident greedy NMS -------
// 4 waves per block, each wave owns one (image,class) bucket. No LDS, no barriers.
__global__ __launch_bounds__(256) void nms_kernel(const float* __restrict__ p,
                                                  const int* __restrict__ cnt,
                                                  const u64* __restrict__ bucketKey,
                                                  u64* __restrict__ accKey) {
#pragma clang fp contract(off)
    int lane = threadIdx.x & 63;
    int bkt = (blockIdx.x << 2) | (threadIdx.x >> 6);
    int b = bkt / NCLS, c = bkt - b * NCLS;
    int n = cnt[bkt * CNTPAD]; if (n > CAP) n = CAP;

    // ---- load keys: element pos = r*64 + lane
    u64 key[8];
#pragma unroll
    for (int r = 0; r < 8; r++) {
        int pos = (r << 6) | lane;
        key[r] = (pos < n) ? bucketKey[(long)bkt * CAP + pos] : 0ULL;
    }

    // ---- in-register bitonic sort, descending over pos = r*64+lane
    // cross-lane step (j<64): partner lane^j via shfl_xor
    auto CE_lane = [&](int k, int j) {
#pragma unroll
        for (int r = 0; r < 8; r++) {
            u64 part = shflx64(key[r], j);
            int pos = (r << 6) | lane;
            bool keepmax = (((pos & k) == 0) == ((lane & j) == 0));
            u64 mx = (key[r] > part) ? key[r] : part;
            u64 mn = (key[r] > part) ? part : key[r];
            key[r] = keepmax ? mx : mn;
        }
    };

#pragma unroll
    for (int k = 2; k <= 64; k <<= 1)
        for (int j = k >> 1; j > 0; j >>= 1)
            CE_lane(k, j);

    // in-lane steps (j = m*64): partner r^m, direction from (r<<6)&k
#define CE_REG(K, M)                                                   \
    {                                                                  \
        _Pragma("unroll")                                              \
        for (int r = 0; r < 8; r++) if (!(r & (M))) {                  \
            int r2 = r | (M);                                          \
            u64 a = key[r], d = key[r2];                               \
            bool desc = (((r << 6) & (K)) == 0);                       \
            u64 hi = (a > d) ? a : d, lo = (a > d) ? d : a;            \
            key[r]  = desc ? hi : lo;                                  \
            key[r2] = desc ? lo : hi;                                  \
        }                                                              \
    }

    CE_REG(128, 1)
    for (int j = 32; j > 0; j >>= 1) CE_lane(128, j);
    CE_REG(256, 2) CE_REG(256, 1)
    for (int j = 32; j > 0; j >>= 1) CE_lane(256, j);
    CE_REG(512, 4) CE_REG(512, 2) CE_REG(512, 1)
    for (int j = 32; j > 0; j >>= 1) CE_lane(512, j);
#undef CE_REG

    // ---- gather boxes into registers (bit-exact ref op order: xyxy then +c*4096)
    float off = (float)c * 4096.0f;
    float rx1[8], ry1[8], rx2[8], ry2[8], rar[8];
    int live = 0;
#pragma unroll
    for (int r = 0; r < 8; r++) {
        int pos = (r << 6) | lane;
        rx1[r] = 0.f; ry1[r] = 0.f; rx2[r] = 0.f; ry2[r] = 0.f; rar[r] = 0.f;
        if (pos < n) {
            int idx = 32767 - (int)((key[r] >> 7) & 32767);
            const float* q = p + ((long)b * NBOX + idx) * CH;
            float x = q[0], y = q[1], w = q[2], h = q[3];
            float hw = w * 0.5f, hh = h * 0.5f;
            rx1[r] = (x - hw) + off; ry1[r] = (y - hh) + off;
            rx2[r] = (x + hw) + off; ry2[r] = (y + hh) + off;
            rar[r] = (rx2[r] - rx1[r]) * (ry2[r] - ry1[r]);
            live |= 1 << r;
        }
    }

    // ---- greedy: at most ACC iterations (only first ACC accepted are ever used)
    long obase = (long)bkt * ACC;
    int nacc = 0;
    for (;;) {
        // find smallest live pos (highest remaining score)
        int i = -1;
#pragma unroll
        for (int r = 0; r < 8; r++) {
            u64 mr = __ballot((live >> r) & 1);
            if (i < 0 && mr) i = (r << 6) + (int)__ffsll((long long)mr) - 1;
        }
        if (i < 0) break;
        int ro = i >> 6, owner = i & 63;

        // select owner's slot ro (uniform) from register arrays
        u64 kk; float sX1, sY1, sX2, sY2, sA;
        switch (ro) {
            case 0: kk=key[0]; sX1=rx1[0]; sY1=ry1[0]; sX2=rx2[0]; sY2=ry2[0]; sA=rar[0]; break;
            case 1: kk=key[1]; sX1=rx1[1]; sY1=ry1[1]; sX2=rx2[1]; sY2=ry2[1]; sA=rar[1]; break;
            case 2: kk=key[2]; sX1=rx1[2]; sY1=ry1[2]; sX2=rx2[2]; sY2=ry2[2]; sA=rar[2]; break;
            case 3: kk=key[3]; sX1=rx1[3]; sY1=ry1[3]; sX2=rx2[3]; sY2=ry2[3]; sA=rar[3]; break;
            case 4: kk=key[4]; sX1=rx1[4]; sY1=ry1[4]; sX2=rx2[4]; sY2=ry2[4]; sA=rar[4]; break;
            case 5: kk=key[5]; sX1=rx1[5]; sY1=ry1[5]; sX2=rx2[5]; sY2=ry2[5]; sA=rar[5]; break;
            case 6: kk=key[6]; sX1=rx1[6]; sY1=ry1[6]; sX2=rx2[6]; sY2=ry2[6]; sA=rar[6]; break;
            default:kk=key[7]; sX1=rx1[7]; sY1=ry1[7]; sX2=rx2[7]; sY2=ry2[7]; sA=rar[7]; break;
        }
        if (lane == owner) {
            accKey[obase + nacc] = kk;
            live &= ~(1 << ro);
        }
        nacc++;
        if (nacc == ACC) break;

        // broadcast accepted box
        float X1 = __shfl(sX1, owner), Y1 = __shfl(sY1, owner);
        float X2 = __shfl(sX2, owner), Y2 = __shfl(sY2, owner);
        float A  = __shfl(sA,  owner);

        // suppress my live boxes with IoU > 0.45
#pragma unroll
        for (int r = 0; r < 8; r++) {
            if ((live >> r) & 1) {
                float xx1 = fmaxf(X1, rx1[r]);
                float yy1 = fmaxf(Y1, ry1[r]);
                float xx2 = fminf(X2, rx2[r]);
                float yy2 = fminf(Y2, ry2[r]);
                float inter = fmaxf(xx2 - xx1, 0.0f) * fmaxf(yy2 - yy1, 0.0f);
                float uni = (A + rar[r]) - inter;
                if (inter / uni > 0.45f) live &= ~(1 << r);
            }
        }
    }
    // zero-fill the tail
    for (int t = nacc + lane; t < ACC; t += 64) accKey[obase + t] = 0ULL;
}

// ---------------- kernel C: per-image merge of 80 sorted lists -> top 300 ------
__global__ __launch_bounds__(256) void merge_kernel(const float* __restrict__ p,
                                                    const u64* __restrict__ accKey,
                                                    float* __restrict__ outRows,
                                                    float* __restrict__ outKeep) {
#pragma clang fp contract(off)
    __shared__ u64 keys[4096];
    int tid = threadIdx.x, b = blockIdx.x;
    for (int t = tid; t < 4096; t += 256)
        keys[t] = (t < NCLS * ACC) ? accKey[(long)b * NCLS * ACC + t] : 0ULL;
    __syncthreads();

    for (int k = 2; k <= 4096; k <<= 1)
        for (int j = k >> 1; j > 0; j >>= 1) {
            for (int t = tid; t < 2048; t += 256) {
                int i  = ((t & ~(j - 1)) << 1) | (t & (j - 1));
                int pj = i | j;
                u64 a = keys[i], d = keys[pj];
                if (((i & k) == 0) ? (a < d) : (a > d)) { keys[i] = d; keys[pj] = a; }
            }
            __syncthreads();
        }

    for (int t = tid; t < MAXDET; t += 256) {
        u64 key = keys[t];
        float r0 = 0, r1 = 0, r2 = 0, r3 = 0, r4 = 0, r5 = 0, kp = 0;
        if (key) {
            int cc  = (int)(key & 127);
            int idx = 32767 - (int)((key >> 7) & 32767);
            float conf = __uint_as_float((unsigned)(key >> 22));
            long pb = ((long)b * NBOX + idx) * CH;
            float x = p[pb], y = p[pb + 1], w = p[pb + 2], h = p[pb + 3];
            float hw = w * 0.5f, hh = h * 0.5f;
            r0 = x - hw; r1 = y - hh; r2 = x + hw; r3 = y + hh;
            r4 = conf; r5 = (float)cc; kp = 1.0f;
        }
        float* row = outRows + ((long)b * MAXDET + t) * 6;
        row[0] = r0; row[1] = r1; row[2] = r2;
        row[3] = r3; row[4] = r4; row[5] = r5;
        outKeep[b * MAXDET + t] = kp;
    }
}

extern "C" void kernel_launch(void* const* d_in, const int* in_sizes, int n_in,
                              void* d_out, int out_size, void* d_ws, size_t ws_size,
                              hipStream_t stream) {
    const float* p = (const float*)d_in[0];
    float* out = (float*)d_out;

    char* ws = (char*)d_ws;
    int* cnt = (int*)ws;                                   // 1280 * 64B padded counters
    u64* bucketKey = (u64*)(ws + BATCH * NCLS * CNTPAD * 4);               // 5.24 MB
    u64* accKey    = (u64*)(ws + BATCH * NCLS * CNTPAD * 4
                               + (size_t)BATCH * NCLS * CAP * 8);          // 491 KB

    hipMemsetAsync(cnt, 0, BATCH * NCLS * CNTPAD * sizeof(int), stream);
    pre_kernel<<<(BATCH * NBOX) / RPB, 256, 0, stream>>>(p, cnt, bucketKey);
    nms_kernel<<<BATCH * NCLS / 4, 256, 0, stream>>>(p, cnt, bucketKey, accKey);
    merge_kernel<<<BATCH, 256, 0, stream>>>(p, accKey, out, out + (size_t)BATCH * MAXDET * 6);
}

// Round 5
// 306.425 us; speedup vs baseline: 2.4753x; 1.2446x over previous
//
#include <hip/hip_runtime.h>
#include <cstdint>
#include <cfloat>

#define BATCH 16
#define NBOX 25200
#define CH 85
#define NCLS 80
#define CAP 512
#define ACC 48
#define MAXDET 300
#define RPB 128      // rows per block in pre_kernel
#define CNTPAD 16    // ints per counter slot (64B line) to kill atomic line contention

typedef unsigned long long u64;

__device__ __forceinline__ u64 shflx64(u64 v, int m) {
    int lo = __shfl_xor((int)(unsigned)(v & 0xffffffffu), m);
    int hi = __shfl_xor((int)(unsigned)(v >> 32), m);
    return ((u64)(unsigned)hi << 32) | (u64)(unsigned)lo;
}

// ---------------- kernel A: staged per-row conf/argmax + bucket by (image,class)
__global__ __launch_bounds__(256) void pre_kernel(const float* __restrict__ p,
                                                  int* __restrict__ cnt,
                                                  u64* __restrict__ bucketKey) {
#pragma clang fp contract(off)
    __shared__ float s[RPB * CH];          // 43,520 B
    int tid = threadIdx.x;
    long blockRow = (long)blockIdx.x * RPB;

    // async global->LDS staging, 16B/lane, lane-contiguous (wave-uniform base + lane*16)
    const float4* p4 = (const float4*)(p + blockRow * CH);
    float4* s4 = (float4*)s;
    for (int t = tid; t < RPB * CH / 4; t += 256) {
        __builtin_amdgcn_global_load_lds(
            (const __attribute__((address_space(1))) void*)(p4 + t),
            (__attribute__((address_space(3))) void*)(s4 + (t & ~63)),
            16, 0, 0);
    }
    __syncthreads();

    int r = tid >> 1;                      // row 0..127
    int half = tid & 1;                    // classes [0,40) vs [40,80)
    const float* row = s + r * CH;
    float obj = row[4];

    float v = -FLT_MAX; int c = 1000;
    int c0 = half * 40;
    for (int k = 0; k < 40; k++) {
        float sc = row[5 + c0 + k] * obj;  // multiply-first, matches reference
        int cc = c0 + k;
        if (sc > v) { v = sc; c = cc; }    // strict > keeps first max
    }
    float v2 = __shfl_xor(v, 1);
    int   cz = __shfl_xor(c, 1);
    if (v2 > v || (v2 == v && cz < c)) { v = v2; c = cz; }

    if (half == 0 && obj > 0.25f && v > 0.25f) {
        int wid = (int)blockRow + r;
        int b   = wid / NBOX;
        int idx = wid - b * NBOX;          // < 25200 < 2^15
        u64 key = ((u64)__float_as_uint(v) << 22) | ((u64)(32767 - idx) << 7) | (u64)c;
        int bkt = b * NCLS + c;
        int pos = atomicAdd(&cnt[bkt * CNTPAD], 1);
        if (pos < CAP) bucketKey[(long)bkt * CAP + pos] = key;
    }
}

// ---------------- kernel B: wave-per-bucket register-resident greedy NMS -------
__global__ __launch_bounds__(256) void nms_kernel(const float* __restrict__ p,
                                                  const int* __restrict__ cnt,
                                                  const u64* __restrict__ bucketKey,
                                                  u64* __restrict__ accKey) {
#pragma clang fp contract(off)
    int lane = threadIdx.x & 63;
    int bkt = (blockIdx.x << 2) | (threadIdx.x >> 6);
    int b = bkt / NCLS, c = bkt - b * NCLS;
    int n = cnt[bkt * CNTPAD]; if (n > CAP) n = CAP;

    u64 key[8];
#pragma unroll
    for (int r = 0; r < 8; r++) {
        int pos = (r << 6) | lane;
        key[r] = (pos < n) ? bucketKey[(long)bkt * CAP + pos] : 0ULL;
    }

    auto CE_lane = [&](int k, int j) {
#pragma unroll
        for (int r = 0; r < 8; r++) {
            u64 part = shflx64(key[r], j);
            int pos = (r << 6) | lane;
            bool keepmax = (((pos & k) == 0) == ((lane & j) == 0));
            u64 mx = (key[r] > part) ? key[r] : part;
            u64 mn = (key[r] > part) ? part : key[r];
            key[r] = keepmax ? mx : mn;
        }
    };

#pragma unroll
    for (int k = 2; k <= 64; k <<= 1)
        for (int j = k >> 1; j > 0; j >>= 1)
            CE_lane(k, j);

#define CE_REG(K, M)                                                   \
    {                                                                  \
        _Pragma("unroll")                                              \
        for (int r = 0; r < 8; r++) if (!(r & (M))) {                  \
            int r2 = r | (M);                                          \
            u64 a = key[r], d = key[r2];                               \
            bool desc = (((r << 6) & (K)) == 0);                       \
            u64 hi = (a > d) ? a : d, lo = (a > d) ? d : a;            \
            key[r]  = desc ? hi : lo;                                  \
            key[r2] = desc ? lo : hi;                                  \
        }                                                              \
    }

    CE_REG(128, 1)
    for (int j = 32; j > 0; j >>= 1) CE_lane(128, j);
    CE_REG(256, 2) CE_REG(256, 1)
    for (int j = 32; j > 0; j >>= 1) CE_lane(256, j);
    CE_REG(512, 4) CE_REG(512, 2) CE_REG(512, 1)
    for (int j = 32; j > 0; j >>= 1) CE_lane(512, j);
#undef CE_REG

    float off = (float)c * 4096.0f;
    float rx1[8], ry1[8], rx2[8], ry2[8], rar[8];
    int live = 0;
#pragma unroll
    for (int r = 0; r < 8; r++) {
        int pos = (r << 6) | lane;
        rx1[r] = 0.f; ry1[r] = 0.f; rx2[r] = 0.f; ry2[r] = 0.f; rar[r] = 0.f;
        if (pos < n) {
            int idx = 32767 - (int)((key[r] >> 7) & 32767);
            const float* q = p + ((long)b * NBOX + idx) * CH;
            float x = q[0], y = q[1], w = q[2], h = q[3];
            float hw = w * 0.5f, hh = h * 0.5f;
            rx1[r] = (x - hw) + off; ry1[r] = (y - hh) + off;
            rx2[r] = (x + hw) + off; ry2[r] = (y + hh) + off;
            rar[r] = (rx2[r] - rx1[r]) * (ry2[r] - ry1[r]);
            live |= 1 << r;
        }
    }

    long obase = (long)bkt * ACC;
    int nacc = 0;
    for (;;) {
        int i = -1;
#pragma unroll
        for (int r = 0; r < 8; r++) {
            u64 mr = __ballot((live >> r) & 1);
            if (i < 0 && mr) i = (r << 6) + (int)__ffsll((long long)mr) - 1;
        }
        if (i < 0) break;
        int ro = i >> 6, owner = i & 63;

        u64 kk; float sX1, sY1, sX2, sY2, sA;
        switch (ro) {
            case 0: kk=key[0]; sX1=rx1[0]; sY1=ry1[0]; sX2=rx2[0]; sY2=ry2[0]; sA=rar[0]; break;
            case 1: kk=key[1]; sX1=rx1[1]; sY1=ry1[1]; sX2=rx2[1]; sY2=ry2[1]; sA=rar[1]; break;
            case 2: kk=key[2]; sX1=rx1[2]; sY1=ry1[2]; sX2=rx2[2]; sY2=ry2[2]; sA=rar[2]; break;
            case 3: kk=key[3]; sX1=rx1[3]; sY1=ry1[3]; sX2=rx2[3]; sY2=ry2[3]; sA=rar[3]; break;
            case 4: kk=key[4]; sX1=rx1[4]; sY1=ry1[4]; sX2=rx2[4]; sY2=ry2[4]; sA=rar[4]; break;
            case 5: kk=key[5]; sX1=rx1[5]; sY1=ry1[5]; sX2=rx2[5]; sY2=ry2[5]; sA=rar[5]; break;
            case 6: kk=key[6]; sX1=rx1[6]; sY1=ry1[6]; sX2=rx2[6]; sY2=ry2[6]; sA=rar[6]; break;
            default:kk=key[7]; sX1=rx1[7]; sY1=ry1[7]; sX2=rx2[7]; sY2=ry2[7]; sA=rar[7]; break;
        }
        if (lane == owner) {
            accKey[obase + nacc] = kk;
            live &= ~(1 << ro);
        }
        nacc++;
        if (nacc == ACC) break;

        float X1 = __shfl(sX1, owner), Y1 = __shfl(sY1, owner);
        float X2 = __shfl(sX2, owner), Y2 = __shfl(sY2, owner);
        float A  = __shfl(sA,  owner);

#pragma unroll
        for (int r = 0; r < 8; r++) {
            if ((live >> r) & 1) {
                float xx1 = fmaxf(X1, rx1[r]);
                float yy1 = fmaxf(Y1, ry1[r]);
                float xx2 = fminf(X2, rx2[r]);
                float yy2 = fminf(Y2, ry2[r]);
                float inter = fmaxf(xx2 - xx1, 0.0f) * fmaxf(yy2 - yy1, 0.0f);
                float uni = (A + rar[r]) - inter;
                if (inter / uni > 0.45f) live &= ~(1 << r);
            }
        }
    }
    for (int t = nacc + lane; t < ACC; t += 64) accKey[obase + t] = 0ULL;
}

// ---------------- kernel C: rank-based merge, no sort, no barriers -------------
// grid (15, 16): 256 keys per block. rank(key) = own_pos + sum over other
// classes of count(entries > key), each count a 6-step binary search in LDS.
// Writes out[rank] directly iff rank < 300; output pre-zeroed by memset.
__global__ __launch_bounds__(256) void merge_kernel(const float* __restrict__ p,
                                                    const u64* __restrict__ accKey,
                                                    float* __restrict__ outRows,
                                                    float* __restrict__ outKeep) {
#pragma clang fp contract(off)
    __shared__ u64 L[NCLS * ACC];          // 30,720 B
    int tid = threadIdx.x;
    int b = blockIdx.y;
    const u64* src = accKey + (long)b * NCLS * ACC;
    for (int t = tid; t < NCLS * ACC; t += 256) L[t] = src[t];
    __syncthreads();

    int g = blockIdx.x * 256 + tid;        // 0..3839
    u64 key = L[g];
    if (key == 0ULL) return;
    int cOwn = g / ACC;
    int rank = g - cOwn * ACC;             // entries before me in my (desc) list are > me

    for (int d = 1; d < NCLS; d++) {
        int c2 = cOwn + d; if (c2 >= NCLS) c2 -= NCLS;
        const u64* Lc = L + c2 * ACC;      // sorted desc, zero-padded
        int cn = 0;
#pragma unroll
        for (int s2 = 32; s2; s2 >>= 1) {
            int nc = cn + s2;
            if (nc <= ACC && Lc[nc - 1] > key) cn = nc;
        }
        rank += cn;
        if (rank >= MAXDET) return;        // rank only grows; prune
    }

    int cc  = (int)(key & 127);
    int idx = 32767 - (int)((key >> 7) & 32767);
    float conf = __uint_as_float((unsigned)(key >> 22));
    const float* q = p + ((long)b * NBOX + idx) * CH;
    float x = q[0], y = q[1], w = q[2], h = q[3];
    float hw = w * 0.5f, hh = h * 0.5f;
    float* row = outRows + ((long)b * MAXDET + rank) * 6;
    row[0] = x - hw; row[1] = y - hh; row[2] = x + hw; row[3] = y + hh;
    row[4] = conf;   row[5] = (float)cc;
    outKeep[b * MAXDET + rank] = 1.0f;
}

extern "C" void kernel_launch(void* const* d_in, const int* in_sizes, int n_in,
                              void* d_out, int out_size, void* d_ws, size_t ws_size,
                              hipStream_t stream) {
    const float* p = (const float*)d_in[0];
    float* out = (float*)d_out;

    char* ws = (char*)d_ws;
    int* cnt = (int*)ws;                                   // 1280 * 64B padded counters
    u64* bucketKey = (u64*)(ws + BATCH * NCLS * CNTPAD * 4);               // 5.24 MB
    u64* accKey    = (u64*)(ws + BATCH * NCLS * CNTPAD * 4
                               + (size_t)BATCH * NCLS * CAP * 8);          // 491 KB

    hipMemsetAsync(cnt, 0, BATCH * NCLS * CNTPAD * sizeof(int), stream);
    hipMemsetAsync(out, 0, (size_t)out_size * sizeof(float), stream);
    pre_kernel<<<(BATCH * NBOX) / RPB, 256, 0, stream>>>(p, cnt, bucketKey);
    nms_kernel<<<BATCH * NCLS / 4, 256, 0, stream>>>(p, cnt, bucketKey, accKey);
    dim3 gM(NCLS * ACC / 256, BATCH);
    merge_kernel<<<gM, 256, 0, stream>>>(p, accKey, out, out + (size_t)BATCH * MAXDET * 6);
}